// Round 1
// baseline (258.451 us; speedup 1.0000x reference)
//
#include <hip/hip_runtime.h>

#define SS 2048
#define BB 32
#define DD 1024
#define HH 16

typedef unsigned short u16;
typedef unsigned int u32;
using f32x4 = __attribute__((ext_vector_type(4))) float;
using bf16x8 = __attribute__((ext_vector_type(8))) short;

__device__ __forceinline__ u16 f2bf(float x) {
  union { float f; u32 u; } c; c.f = x;
  u32 r = c.u + 0x7fffu + ((c.u >> 16) & 1u);
  return (u16)(r >> 16);
}
__device__ __forceinline__ float bf2f(u32 h) {
  union { u32 u; float f; } c; c.u = h << 16; return c.f;
}
// XOR swizzle: row stride 2048B; flip byte bits 4..6 by (row&7) -> spreads
// the 16-lane same-column ds_read_b128 across 8 distinct 16B slots (2-way = free).
__device__ __forceinline__ int swzb(int row, int col) {
  return ((row << 11) + (col << 1)) ^ ((row & 7) << 4);
}
__device__ __forceinline__ void st_lds8(u16* base, int row, int col, const u16* v) {
  uint4 pk;
  pk.x = (u32)v[0] | ((u32)v[1] << 16);
  pk.y = (u32)v[2] | ((u32)v[3] << 16);
  pk.z = (u32)v[4] | ((u32)v[5] << 16);
  pk.w = (u32)v[6] | ((u32)v[7] << 16);
  *reinterpret_cast<uint4*>(reinterpret_cast<char*>(base) + swzb(row, col)) = pk;
}
__device__ __forceinline__ uint4 ld_lds8(const u16* base, int row, int col) {
  return *reinterpret_cast<const uint4*>(reinterpret_cast<const char*>(base) + swzb(row, col));
}
__device__ __forceinline__ bf16x8 ld_afrag(const u16* base, int row, int col) {
  return *reinterpret_cast<const bf16x8*>(reinterpret_cast<const char*>(base) + swzb(row, col));
}
__device__ __forceinline__ void st_lds1(u16* base, int row, int col, u16 v) {
  *reinterpret_cast<u16*>(reinterpret_cast<char*>(base) + swzb(row, col)) = v;
}

// Repack W [H][128][64] f32 -> bf16 MFMA B-fragment order:
// Wf[((h*4+ks)*4+nt)*64 + lane][j] = bf16( W[h][ks*32 + 8*(lane>>4)+j][nt*16 + (lane&15)] )
__global__ void prep_w(const float* __restrict__ W, u16* __restrict__ Wf) {
  const int o = blockIdx.x * 256 + threadIdx.x;   // 16384 threads: (tile, lane)
  const int l = o & 63;
  const int tile = o >> 6;                        // h*16 + ks*4 + nt
  const int nt = tile & 3, ks = (tile >> 2) & 3, h = tile >> 4;
  const int d = nt * 16 + (l & 15);
  const int kb = ks * 32 + 8 * (l >> 4);
  u16 v[8];
#pragma unroll
  for (int j = 0; j < 8; ++j) v[j] = f2bf(W[(h * 128 + kb + j) * 64 + d]);
  uint4 pk;
  pk.x = (u32)v[0] | ((u32)v[1] << 16);
  pk.y = (u32)v[2] | ((u32)v[3] << 16);
  pk.z = (u32)v[4] | ((u32)v[5] << 16);
  pk.w = (u32)v[6] | ((u32)v[7] << 16);
  reinterpret_cast<uint4*>(Wf)[o] = pk;
}

__global__ __launch_bounds__(1024) void lienet_main(
    const float* __restrict__ src, const u16* __restrict__ Wf,
    const float* __restrict__ bias, const float* __restrict__ gamma,
    const float* __restrict__ beta, float* __restrict__ out) {
  __shared__ __align__(16) u16 cbuf[BB * DD];  // c = LN(src[t-1]) bf16, later reused for y
  __shared__ __align__(16) u16 xbuf[BB * DD];  // x = src[t] bf16

  // XCD-bijective swizzle: blocks t and t+1 land on the same XCD -> src[t]
  // second read (as c-source) hits that XCD's L2. 2048 % 8 == 0 -> bijective.
  const int bid = blockIdx.x;
  const int t = (bid & 7) * 256 + (bid >> 3);

  const int tid = threadIdx.x;
  const int wave = tid >> 6;
  const int lane = tid & 63;
  const int colbase = lane * 16;  // this lane's 16-element column chunk

  // ---------------- staging: wave w owns rows 2w, 2w+1 ----------------
#pragma unroll
  for (int rr = 0; rr < 2; ++rr) {
    const int row = wave * 2 + rr;
    {  // x = src[t][row][:] -> bf16 -> xbuf
      const float4* p = reinterpret_cast<const float4*>(src + ((size_t)t * BB + row) * DD + colbase);
      u16 v[16];
#pragma unroll
      for (int q = 0; q < 4; ++q) {
        float4 f = p[q];
        v[q * 4 + 0] = f2bf(f.x); v[q * 4 + 1] = f2bf(f.y);
        v[q * 4 + 2] = f2bf(f.z); v[q * 4 + 3] = f2bf(f.w);
      }
      st_lds8(xbuf, row, colbase, v);
      st_lds8(xbuf, row, colbase + 8, v + 8);
    }
    if (t == 0) {  // c0 = zeros (NOT layer-normed)
      u16 v[16];
#pragma unroll
      for (int j = 0; j < 16; ++j) v[j] = 0;
      st_lds8(cbuf, row, colbase, v);
      st_lds8(cbuf, row, colbase + 8, v + 8);
    } else {  // c = LN(src[t-1][row][:]) -> bf16 -> cbuf
      const float4* p = reinterpret_cast<const float4*>(src + ((size_t)(t - 1) * BB + row) * DD + colbase);
      float f[16];
      float s1 = 0.f, s2 = 0.f;
#pragma unroll
      for (int q = 0; q < 4; ++q) {
        float4 fv = p[q];
        f[q * 4 + 0] = fv.x; f[q * 4 + 1] = fv.y;
        f[q * 4 + 2] = fv.z; f[q * 4 + 3] = fv.w;
      }
#pragma unroll
      for (int j = 0; j < 16; ++j) { s1 += f[j]; s2 += f[j] * f[j]; }
#pragma unroll
      for (int off = 32; off; off >>= 1) { s1 += __shfl_xor(s1, off); s2 += __shfl_xor(s2, off); }
      const float mu = s1 * (1.f / 1024.f);
      const float rs = rsqrtf(s2 * (1.f / 1024.f) - mu * mu + 1e-5f);
      const float4* gp = reinterpret_cast<const float4*>(gamma + colbase);
      const float4* bp = reinterpret_cast<const float4*>(beta + colbase);
      u16 v[16];
#pragma unroll
      for (int q = 0; q < 4; ++q) {
        float4 gv = gp[q], bv = bp[q];
        v[q * 4 + 0] = f2bf((f[q * 4 + 0] - mu) * rs * gv.x + bv.x);
        v[q * 4 + 1] = f2bf((f[q * 4 + 1] - mu) * rs * gv.y + bv.y);
        v[q * 4 + 2] = f2bf((f[q * 4 + 2] - mu) * rs * gv.z + bv.z);
        v[q * 4 + 3] = f2bf((f[q * 4 + 3] - mu) * rs * gv.w + bv.w);
      }
      st_lds8(cbuf, row, colbase, v);
      st_lds8(cbuf, row, colbase + 8, v + 8);
    }
  }
  __syncthreads();

  // ---------------- per-head matmul: head h = wave ----------------
  // y[b][d] = sum_k cat[b][k] * W[h][k][d],  M=32 (2 mtiles), N=64 (4 ntiles), K=128 (4 kslices)
  const int h = wave;
  f32x4 acc[2][4];
#pragma unroll
  for (int mt = 0; mt < 2; ++mt)
#pragma unroll
    for (int nt = 0; nt < 4; ++nt) acc[mt][nt] = (f32x4){0.f, 0.f, 0.f, 0.f};

  const int arow = lane & 15;
  const int kb = 8 * (lane >> 4);
#pragma unroll
  for (int ks = 0; ks < 4; ++ks) {
    const u16* sb = (ks < 2) ? cbuf : xbuf;            // cat = [c ; x]
    const int col = h * 64 + (ks & 1) * 32 + kb;       // within-row bf16 column
    bf16x8 a0 = ld_afrag(sb, arow, col);
    bf16x8 a1 = ld_afrag(sb, arow + 16, col);
    const uint4* wp = reinterpret_cast<const uint4*>(Wf) + ((h * 4 + ks) * 4) * 64 + lane;
#pragma unroll
    for (int nt = 0; nt < 4; ++nt) {
      uint4 wv = wp[nt * 64];
      bf16x8 bfr = *reinterpret_cast<bf16x8*>(&wv);
      acc[0][nt] = __builtin_amdgcn_mfma_f32_16x16x32_bf16(a0, bfr, acc[0][nt], 0, 0, 0);
      acc[1][nt] = __builtin_amdgcn_mfma_f32_16x16x32_bf16(a1, bfr, acc[1][nt], 0, 0, 0);
    }
  }

  // epilogue: + bias, exact GELU, bf16 -> cbuf (reused as y buffer; only this
  // wave's head-columns are overwritten, and this wave is done reading them)
#pragma unroll
  for (int nt = 0; nt < 4; ++nt) {
    const int dcol = h * 64 + nt * 16 + (lane & 15);
    const float bv = bias[dcol];
#pragma unroll
    for (int mt = 0; mt < 2; ++mt) {
#pragma unroll
      for (int r = 0; r < 4; ++r) {
        const int row = mt * 16 + (lane >> 4) * 4 + r;  // D row = 4*(lane>>4)+r
        const float v = acc[mt][nt][r] + bv;
        const float gel = 0.5f * v * (1.0f + erff(v * 0.70710678118654752f));
        st_lds1(cbuf, row, dcol, f2bf(gel));
      }
    }
  }
  __syncthreads();

  // ---------------- final LN over y rows, write fp32 out ----------------
#pragma unroll
  for (int rr = 0; rr < 2; ++rr) {
    const int row = wave * 2 + rr;
    uint4 g0 = ld_lds8(cbuf, row, colbase);
    uint4 g1 = ld_lds8(cbuf, row, colbase + 8);
    float vals[16];
    vals[0] = bf2f(g0.x & 0xffffu); vals[1] = bf2f(g0.x >> 16);
    vals[2] = bf2f(g0.y & 0xffffu); vals[3] = bf2f(g0.y >> 16);
    vals[4] = bf2f(g0.z & 0xffffu); vals[5] = bf2f(g0.z >> 16);
    vals[6] = bf2f(g0.w & 0xffffu); vals[7] = bf2f(g0.w >> 16);
    vals[8] = bf2f(g1.x & 0xffffu); vals[9] = bf2f(g1.x >> 16);
    vals[10] = bf2f(g1.y & 0xffffu); vals[11] = bf2f(g1.y >> 16);
    vals[12] = bf2f(g1.z & 0xffffu); vals[13] = bf2f(g1.z >> 16);
    vals[14] = bf2f(g1.w & 0xffffu); vals[15] = bf2f(g1.w >> 16);
    float s1 = 0.f, s2 = 0.f;
#pragma unroll
    for (int j = 0; j < 16; ++j) { s1 += vals[j]; s2 += vals[j] * vals[j]; }
#pragma unroll
    for (int off = 32; off; off >>= 1) { s1 += __shfl_xor(s1, off); s2 += __shfl_xor(s2, off); }
    const float mu = s1 * (1.f / 1024.f);
    const float rs = rsqrtf(s2 * (1.f / 1024.f) - mu * mu + 1e-5f);
    const float4* gp = reinterpret_cast<const float4*>(gamma + colbase);
    const float4* bp = reinterpret_cast<const float4*>(beta + colbase);
    float* op = out + ((size_t)t * BB + row) * DD + colbase;
#pragma unroll
    for (int q = 0; q < 4; ++q) {
      float4 gv = gp[q], bv = bp[q];
      float4 o;
      o.x = (vals[q * 4 + 0] - mu) * rs * gv.x + bv.x;
      o.y = (vals[q * 4 + 1] - mu) * rs * gv.y + bv.y;
      o.z = (vals[q * 4 + 2] - mu) * rs * gv.z + bv.z;
      o.w = (vals[q * 4 + 3] - mu) * rs * gv.w + bv.w;
      reinterpret_cast<float4*>(op)[q] = o;
    }
  }
}

extern "C" void kernel_launch(void* const* d_in, const int* in_sizes, int n_in,
                              void* d_out, int out_size, void* d_ws, size_t ws_size,
                              hipStream_t stream) {
  const float* src = (const float*)d_in[0];
  const float* W = (const float*)d_in[1];
  const float* bias = (const float*)d_in[2];
  const float* gamma = (const float*)d_in[3];
  const float* beta = (const float*)d_in[4];
  float* out = (float*)d_out;
  u16* Wf = (u16*)d_ws;  // 256 KB repacked bf16 W fragments

  prep_w<<<64, 256, 0, stream>>>(W, Wf);
  lienet_main<<<SS, 1024, 0, stream>>>(src, Wf, bias, gamma, beta, out);
}

// Round 2
// 228.355 us; speedup vs baseline: 1.1318x; 1.1318x over previous
//
#include <hip/hip_runtime.h>

#define SS 2048
#define BB 32
#define DD 1024
#define HH 16
#define RB 8   // batch rows per block

typedef unsigned short u16;
typedef unsigned int u32;
using f32x4 = __attribute__((ext_vector_type(4))) float;
using bf16x8 = __attribute__((ext_vector_type(8))) short;

__device__ __forceinline__ u16 f2bf(float x) {
  union { float f; u32 u; } c; c.f = x;
  u32 r = c.u + 0x7fffu + ((c.u >> 16) & 1u);
  return (u16)(r >> 16);
}
// XOR swizzle for row-stride-2048B bf16 tiles: spreads same-col cross-row
// ds_read_b128 over 8 distinct 16B slots (A-frag loads), keeps 16B chunks intact.
__device__ __forceinline__ int swzb(int row, int col) {
  return ((row << 11) + (col << 1)) ^ ((row & 7) << 4);
}
__device__ __forceinline__ void st_lds8(u16* base, int row, int col,
                                        float4 a, float4 b) {
  uint4 pk;
  pk.x = (u32)f2bf(a.x) | ((u32)f2bf(a.y) << 16);
  pk.y = (u32)f2bf(a.z) | ((u32)f2bf(a.w) << 16);
  pk.z = (u32)f2bf(b.x) | ((u32)f2bf(b.y) << 16);
  pk.w = (u32)f2bf(b.z) | ((u32)f2bf(b.w) << 16);
  *reinterpret_cast<uint4*>(reinterpret_cast<char*>(base) + swzb(row, col)) = pk;
}
__device__ __forceinline__ void st_lds8z(u16* base, int row, int col) {
  uint4 pk; pk.x = pk.y = pk.z = pk.w = 0u;
  *reinterpret_cast<uint4*>(reinterpret_cast<char*>(base) + swzb(row, col)) = pk;
}
__device__ __forceinline__ bf16x8 ld_afrag(const u16* base, int row, int col) {
  return *reinterpret_cast<const bf16x8*>(reinterpret_cast<const char*>(base) + swzb(row, col));
}
// tanh-form GELU: branch-free, v_exp_f32-based. |err| vs exact erf-GELU < ~3e-4.
__device__ __forceinline__ float gelu_f(float v) {
  const float u2 = 1.5957691216057308f * v * __builtin_fmaf(0.044715f, v * v, 1.0f);
  const float e = __expf(u2);                       // e^(2u)
  const float th = 1.0f - 2.0f * __builtin_amdgcn_rcpf(e + 1.0f);
  return 0.5f * v * (1.0f + th);
}

// Repack W [H][128][64] f32 -> bf16 MFMA B-fragment order:
// Wf[((h*4+ks)*4+nt)*64 + lane][j] = bf16( W[h][ks*32 + 8*(lane>>4)+j][nt*16 + (lane&15)] )
__global__ void prep_w(const float* __restrict__ W, u16* __restrict__ Wf) {
  const int o = blockIdx.x * 256 + threadIdx.x;
  const int l = o & 63;
  const int tile = o >> 6;
  const int nt = tile & 3, ks = (tile >> 2) & 3, h = tile >> 4;
  const int d = nt * 16 + (l & 15);
  const int kb = ks * 32 + 8 * (l >> 4);
  u16 v[8];
#pragma unroll
  for (int j = 0; j < 8; ++j) v[j] = f2bf(W[(h * 128 + kb + j) * 64 + d]);
  uint4 pk;
  pk.x = (u32)v[0] | ((u32)v[1] << 16);
  pk.y = (u32)v[2] | ((u32)v[3] << 16);
  pk.z = (u32)v[4] | ((u32)v[5] << 16);
  pk.w = (u32)v[6] | ((u32)v[7] << 16);
  reinterpret_cast<uint4*>(Wf)[o] = pk;
}

__global__ __launch_bounds__(256, 4) void lienet_main(
    const float* __restrict__ src, const u16* __restrict__ Wf,
    const float* __restrict__ bias, const float* __restrict__ gamma,
    const float* __restrict__ beta, float* __restrict__ out) {
  __shared__ __align__(16) u16 cbuf[RB * DD];   // 16 KB
  __shared__ __align__(16) u16 xbuf[RB * DD];   // 16 KB
  __shared__ float part[4][RB][2];              // per-wave row partial sums

  // bid -> (t, row-group); XCD-bijective: each XCD gets a contiguous t-range,
  // 4 row-groups of t then t+1 -> src[t] x-read and c-read share that XCD's L2.
  const int bid = blockIdx.x;
  const int lin = (bid & 7) * 1024 + (bid >> 3);
  const int t = lin >> 2;
  const int row0 = (lin & 3) * RB;

  const int tid = threadIdx.x;
  const int wave = tid >> 6;
  const int lane = tid & 63;
  const int c0 = lane * 8;  // contiguous 8-col chunk -> conflict-free LDS writes

  // ---------------- staging: wave w owns tile rows 2w, 2w+1 ----------------
#pragma unroll
  for (int rr = 0; rr < 2; ++rr) {
    const int row = wave * 2 + rr;
    const int grow = row0 + row;
    {  // x = src[t][grow][:] -> bf16
      const float* rp = src + ((size_t)t * BB + grow) * DD;
      float4 f0 = *reinterpret_cast<const float4*>(rp + c0);
      float4 f1 = *reinterpret_cast<const float4*>(rp + c0 + 4);
      float4 f2 = *reinterpret_cast<const float4*>(rp + 512 + c0);
      float4 f3 = *reinterpret_cast<const float4*>(rp + 512 + c0 + 4);
      st_lds8(xbuf, row, c0, f0, f1);
      st_lds8(xbuf, row, 512 + c0, f2, f3);
    }
    if (t == 0) {
      st_lds8z(cbuf, row, c0);
      st_lds8z(cbuf, row, 512 + c0);
    } else {  // c = LN(src[t-1][grow][:]) -> bf16
      const float* rp = src + ((size_t)(t - 1) * BB + grow) * DD;
      float f[16];
      *reinterpret_cast<float4*>(f + 0) = *reinterpret_cast<const float4*>(rp + c0);
      *reinterpret_cast<float4*>(f + 4) = *reinterpret_cast<const float4*>(rp + c0 + 4);
      *reinterpret_cast<float4*>(f + 8) = *reinterpret_cast<const float4*>(rp + 512 + c0);
      *reinterpret_cast<float4*>(f + 12) = *reinterpret_cast<const float4*>(rp + 512 + c0 + 4);
      float s1 = 0.f, s2 = 0.f;
#pragma unroll
      for (int j = 0; j < 16; ++j) { s1 += f[j]; s2 += f[j] * f[j]; }
#pragma unroll
      for (int off = 32; off; off >>= 1) { s1 += __shfl_xor(s1, off); s2 += __shfl_xor(s2, off); }
      const float mu = s1 * (1.f / 1024.f);
      const float rs = rsqrtf(s2 * (1.f / 1024.f) - mu * mu + 1e-5f);
      float4 g0 = *reinterpret_cast<const float4*>(gamma + c0);
      float4 g1 = *reinterpret_cast<const float4*>(gamma + c0 + 4);
      float4 g2 = *reinterpret_cast<const float4*>(gamma + 512 + c0);
      float4 g3 = *reinterpret_cast<const float4*>(gamma + 512 + c0 + 4);
      float4 b0 = *reinterpret_cast<const float4*>(beta + c0);
      float4 b1 = *reinterpret_cast<const float4*>(beta + c0 + 4);
      float4 b2 = *reinterpret_cast<const float4*>(beta + 512 + c0);
      float4 b3 = *reinterpret_cast<const float4*>(beta + 512 + c0 + 4);
      float4 o0, o1, o2, o3;
      o0.x = (f[0] - mu) * rs * g0.x + b0.x;  o0.y = (f[1] - mu) * rs * g0.y + b0.y;
      o0.z = (f[2] - mu) * rs * g0.z + b0.z;  o0.w = (f[3] - mu) * rs * g0.w + b0.w;
      o1.x = (f[4] - mu) * rs * g1.x + b1.x;  o1.y = (f[5] - mu) * rs * g1.y + b1.y;
      o1.z = (f[6] - mu) * rs * g1.z + b1.z;  o1.w = (f[7] - mu) * rs * g1.w + b1.w;
      o2.x = (f[8] - mu) * rs * g2.x + b2.x;  o2.y = (f[9] - mu) * rs * g2.y + b2.y;
      o2.z = (f[10] - mu) * rs * g2.z + b2.z; o2.w = (f[11] - mu) * rs * g2.w + b2.w;
      o3.x = (f[12] - mu) * rs * g3.x + b3.x; o3.y = (f[13] - mu) * rs * g3.y + b3.y;
      o3.z = (f[14] - mu) * rs * g3.z + b3.z; o3.w = (f[15] - mu) * rs * g3.w + b3.w;
      st_lds8(cbuf, row, c0, o0, o1);
      st_lds8(cbuf, row, 512 + c0, o2, o3);
    }
  }
  __syncthreads();

  // ---------------- matmul: wave w -> heads 4w..4w+3, M=16 (rows 0-7 dup'd) ----------------
  f32x4 acc[4][4];
#pragma unroll
  for (int hh = 0; hh < 4; ++hh)
#pragma unroll
    for (int nt = 0; nt < 4; ++nt) acc[hh][nt] = (f32x4){0.f, 0.f, 0.f, 0.f};

  const int arow = lane & 7;         // rows 8-15 of the MFMA M-dim duplicate rows 0-7
  const int kb = 8 * (lane >> 4);
#pragma unroll
  for (int ks = 0; ks < 4; ++ks) {
    const u16* sb = (ks < 2) ? cbuf : xbuf;  // cat = [c ; x]
#pragma unroll
    for (int hh = 0; hh < 4; ++hh) {
      const int h = wave * 4 + hh;
      bf16x8 a = ld_afrag(sb, arow, h * 64 + (ks & 1) * 32 + kb);
      const uint4* wp = reinterpret_cast<const uint4*>(Wf) + ((h * 4 + ks) * 4) * 64 + lane;
#pragma unroll
      for (int nt = 0; nt < 4; ++nt) {
        uint4 wv = wp[nt * 64];
        bf16x8 bfr = *reinterpret_cast<bf16x8*>(&wv);
        acc[hh][nt] = __builtin_amdgcn_mfma_f32_16x16x32_bf16(a, bfr, acc[hh][nt], 0, 0, 0);
      }
    }
  }

  // ---------------- epilogue: bias + GELU in regs, LN stats via shfl + 256B LDS ----------------
  // lane split: lanes<32 own heads {4w,4w+1}, lanes>=32 own heads {4w+2,4w+3};
  // C rows: (lane>>4)&1 selects rows 0-3 / 4-7 (upper M half is a duplicate).
  const int hilo = lane >> 5;
  const int row4 = 4 * ((lane >> 4) & 1);
  const int cl = lane & 15;
  float gv[2][4][4];
#pragma unroll
  for (int hp = 0; hp < 2; ++hp) {
    const int h_eff = wave * 4 + hp + 2 * hilo;
#pragma unroll
    for (int nt = 0; nt < 4; ++nt) {
      const float bv = bias[h_eff * 64 + nt * 16 + cl];
#pragma unroll
      for (int r = 0; r < 4; ++r) {
        const float v = (hilo ? acc[hp + 2][nt][r] : acc[hp][nt][r]) + bv;
        gv[hp][nt][r] = gelu_f(v);
      }
    }
  }
  float s1[4], s2[4];
#pragma unroll
  for (int r = 0; r < 4; ++r) {
    float a = 0.f, b = 0.f;
#pragma unroll
    for (int hp = 0; hp < 2; ++hp)
#pragma unroll
      for (int nt = 0; nt < 4; ++nt) {
        const float g = gv[hp][nt][r];
        a += g; b += g * g;
      }
    // reduce over the 16 lanes of this (row-group, head-half), then merge head-halves
    a += __shfl_xor(a, 1); b += __shfl_xor(b, 1);
    a += __shfl_xor(a, 2); b += __shfl_xor(b, 2);
    a += __shfl_xor(a, 4); b += __shfl_xor(b, 4);
    a += __shfl_xor(a, 8); b += __shfl_xor(b, 8);
    a += __shfl_xor(a, 32); b += __shfl_xor(b, 32);
    s1[r] = a; s2[r] = b;
  }
  if (lane == 0 || lane == 16) {
#pragma unroll
    for (int r = 0; r < 4; ++r) {
      part[wave][row4 + r][0] = s1[r];
      part[wave][row4 + r][1] = s2[r];
    }
  }
  // preload gamma/beta (hides latency under the barrier)
  float gm[2][4], bt[2][4];
#pragma unroll
  for (int hp = 0; hp < 2; ++hp) {
    const int h_eff = wave * 4 + hp + 2 * hilo;
#pragma unroll
    for (int nt = 0; nt < 4; ++nt) {
      const int dcol = h_eff * 64 + nt * 16 + cl;
      gm[hp][nt] = gamma[dcol];
      bt[hp][nt] = beta[dcol];
    }
  }
  __syncthreads();

  float mu[4], rs[4];
#pragma unroll
  for (int r = 0; r < 4; ++r) {
    const int row = row4 + r;
    const float a = part[0][row][0] + part[1][row][0] + part[2][row][0] + part[3][row][0];
    const float b = part[0][row][1] + part[1][row][1] + part[2][row][1] + part[3][row][1];
    mu[r] = a * (1.f / 1024.f);
    rs[r] = rsqrtf(b * (1.f / 1024.f) - mu[r] * mu[r] + 1e-5f);
  }
#pragma unroll
  for (int hp = 0; hp < 2; ++hp) {
    const int h_eff = wave * 4 + hp + 2 * hilo;
#pragma unroll
    for (int nt = 0; nt < 4; ++nt) {
      const int dcol = h_eff * 64 + nt * 16 + cl;
#pragma unroll
      for (int r = 0; r < 4; ++r) {
        const float o = (gv[hp][nt][r] - mu[r]) * rs[r] * gm[hp][nt] + bt[hp][nt];
        out[((size_t)t * BB + row0 + row4 + r) * DD + dcol] = o;
      }
    }
  }
}

extern "C" void kernel_launch(void* const* d_in, const int* in_sizes, int n_in,
                              void* d_out, int out_size, void* d_ws, size_t ws_size,
                              hipStream_t stream) {
  const float* src = (const float*)d_in[0];
  const float* W = (const float*)d_in[1];
  const float* bias = (const float*)d_in[2];
  const float* gamma = (const float*)d_in[3];
  const float* beta = (const float*)d_in[4];
  float* out = (float*)d_out;
  u16* Wf = (u16*)d_ws;  // 256 KB repacked bf16 W fragments

  prep_w<<<64, 256, 0, stream>>>(W, Wf);
  lienet_main<<<SS * 4, 256, 0, stream>>>(src, Wf, bias, gamma, beta, out);
}